// Round 3
// baseline (279.351 us; speedup 1.0000x reference)
//
#include <hip/hip_runtime.h>
#include <hip/hip_bf16.h>
#include <stdint.h>

// Problem constants (CZT_72533407694901)
#define MM   1840          // M (zoom bins)
#define M2   3680          // 2M rows of W / X
#define NN   512           // N time samples
#define K2   1024          // 2N columns of W
#define CS   8192          // C*S = 32*256
#define MPAD 3712          // Abf row padding (rows 3680..3711 zero-filled by prep)

#define WPREP_BLOCKS (MPAD / 2)        // 1856 blocks, 2 rows each
#define XT_NB        (CS / 32)         // 256 n-tiles
#define XT_KB        (NN / 64)         // 8 k-tiles

// GEMM geometry: 256x256 tile, BK=64, 8 waves (2M x 4N), dbuf LDS, counted vmcnt
#define GBM 256
#define GBN 256
#define NBM2 15            // ceil(3680/256) -> M padded to 3840 via addr clamp
#define NBN2 32            // 8192/256
#define NKT  8             // K=512 / BK=64

typedef __bf16 bf16x8 __attribute__((ext_vector_type(8)));
typedef float  floatx4 __attribute__((ext_vector_type(4)));

// -------------------------------------------------------------------------
// ROUND 2 = MEASUREMENT ROUND. Kernels byte-identical to round 1 (passed,
// 184.6 us). Only change: launch prep x2 and gemm x3 (both idempotent ->
// identical outputs, same work every replay). Timed-window algebra:
//   dur_new = dur_old + prep + 2*gemm
// disambiguates whether the GEMM (~85us, model A) or fixed harness resets
// (model B, gemm ~30us) dominate the 184us window, since top-5 profiling
// currently hides both czt kernels behind ~81us harness fills.
// -------------------------------------------------------------------------

// -------------------------------------------------------------------------
// Kernel 1 (fused prep)
// -------------------------------------------------------------------------
__global__ __launch_bounds__(256) void czt_prep(const float* __restrict__ Wr,
                                                const float* __restrict__ Wi,
                                                const float* __restrict__ ac,
                                                const float* __restrict__ as_,
                                                const float* __restrict__ x,
                                                float* __restrict__ Wout,
                                                __hip_bfloat16* __restrict__ Abf,
                                                __hip_bfloat16* __restrict__ Bxt) {
    __shared__ float tile[64 * 33];
    const int b   = blockIdx.x;
    const int tid = threadIdx.x;

    if (b < WPREP_BLOCKS) {
        const int j = b * 2 + (tid >> 7);
        const int k = (tid & 127) * 4;

        union { __hip_bfloat16 h[4]; uint2 u; } p;
        if (j < M2) {
            const int jj = (j < MM) ? j : j - MM;
            const floatx4 wr = *(const floatx4*)&Wr[(size_t)jj * NN + k];
            const floatx4 wi = *(const floatx4*)&Wi[(size_t)jj * NN + k];
            const floatx4 c  = *(const floatx4*)&ac[k];
            const floatx4 s  = *(const floatx4*)&as_[k];
            floatx4 f, g, a;
            if (j < MM) { f = wr; g = -wi; a = wr * c - wi * s; }
            else        { f = wi; g = wr;  a = wi * c + wr * s; }
#pragma unroll
            for (int e = 0; e < 4; ++e) {
                f[e] = fminf(1.f, fmaxf(-1.f, f[e]));
                g[e] = fminf(1.f, fmaxf(-1.f, g[e]));
            }
            *(floatx4*)&Wout[(size_t)j * K2 + k]      = f;
            *(floatx4*)&Wout[(size_t)j * K2 + NN + k] = g;
            p.h[0] = __float2bfloat16(a[0]);
            p.h[1] = __float2bfloat16(a[1]);
            p.h[2] = __float2bfloat16(a[2]);
            p.h[3] = __float2bfloat16(a[3]);
        } else {
            p.h[0] = p.h[1] = p.h[2] = p.h[3] = __float2bfloat16(0.0f);
        }
        *(uint2*)&Abf[(size_t)j * NN + k] = p.u;
    } else {
        const int tb = b - WPREP_BLOCKS;
        const int n0 = (tb & (XT_NB - 1)) * 32;
        const int k0 = (tb >> 8) * 64;

        const int row = tid >> 2;
        const int c8  = (tid & 3) * 8;
        const floatx4* src = (const floatx4*)&x[(size_t)(k0 + row) * CS + n0 + c8];
        const floatx4 v0 = src[0];
        const floatx4 v1 = src[1];
        float* tr = &tile[row * 33 + c8];
        tr[0] = v0[0]; tr[1] = v0[1]; tr[2] = v0[2]; tr[3] = v0[3];
        tr[4] = v1[0]; tr[5] = v1[1]; tr[6] = v1[2]; tr[7] = v1[3];
        __syncthreads();

        const int oc = tid & 7;
        const int nr = tid >> 3;
        union { __hip_bfloat16 h[8]; uint4 u; } q;
#pragma unroll
        for (int jj = 0; jj < 8; ++jj)
            q.h[jj] = __float2bfloat16(tile[(oc * 8 + jj) * 33 + nr]);
        *(uint4*)&Bxt[(size_t)(n0 + nr) * NN + k0 + oc * 8] = q.u;
    }
}

// -------------------------------------------------------------------------
// Kernel 2: GEMM (identical to round 1)
// -------------------------------------------------------------------------
__device__ __forceinline__ void gload_lds16(const void* g, void* l) {
    __builtin_amdgcn_global_load_lds(
        (const __attribute__((address_space(1))) uint32_t*)g,
        (__attribute__((address_space(3))) uint32_t*)l,
        16, 0, 0);
}

__device__ __forceinline__ void raw_bar() {
    __builtin_amdgcn_sched_barrier(0);
    asm volatile("s_barrier" ::: "memory");
    __builtin_amdgcn_sched_barrier(0);
}

__device__ __forceinline__ void wait_lgkm0() {
    asm volatile("s_waitcnt lgkmcnt(0)" ::: "memory");
    __builtin_amdgcn_sched_barrier(0);
}

__global__ __launch_bounds__(512, 2) void czt_gemm(const __hip_bfloat16* __restrict__ Abf,
                                                   const __hip_bfloat16* __restrict__ Bxt,
                                                   float* __restrict__ Xout) {
    __shared__ __hip_bfloat16 As[2][GBM * 64];
    __shared__ __hip_bfloat16 Bs[2][GBN * 64];

    const int tid  = threadIdx.x;
    const int lane = tid & 63;
    const int w    = tid >> 6;
    const int quad = lane >> 4;
    const int r16  = lane & 15;

    const int b  = blockIdx.x;
    const int wk = (b & 7) * 60 + (b >> 3);
    const int mb = wk % NBM2;
    const int nb = wk / NBM2;
    const int mtile = mb * GBM;
    const int ntile = nb * GBN;

    const int wm = (w >> 2) * 128;
    const int wn = (w & 3) * 64;

    const int rsub   = lane >> 3;
    const int cstage = ((lane & 7) ^ rsub) * 8;

#define STAGE(kt_, bf_)                                                          \
    do {                                                                         \
        _Pragma("unroll")                                                        \
        for (int t4 = 0; t4 < 4; ++t4) {                                         \
            const int rs = w * 32 + t4 * 8;                                      \
            int ar = mtile + rs + rsub;                                          \
            if (ar > MPAD - 1) ar = MPAD - 1;                                    \
            gload_lds16(Abf + (size_t)ar * NN + (kt_) * 64 + cstage,             \
                        &As[(bf_)][rs * 64]);                                    \
            gload_lds16(Bxt + (size_t)(ntile + rs + rsub) * NN + (kt_) * 64 +    \
                            cstage,                                              \
                        &Bs[(bf_)][rs * 64]);                                    \
        }                                                                        \
    } while (0)

    floatx4 acc[8][4] = {};

    STAGE(0, 0);
    STAGE(1, 1);

#pragma unroll
    for (int t = 0; t < NKT; ++t) {
        if (t < NKT - 1) asm volatile("s_waitcnt vmcnt(8)" ::: "memory");
        else             asm volatile("s_waitcnt vmcnt(0)" ::: "memory");
        __builtin_amdgcn_sched_barrier(0);
        raw_bar();
        const int bf_ = t & 1;

        {
            const int pch = ((0 * 4 + quad) ^ (r16 & 7)) * 8;
            bf16x8 af[8], bv[4];
#pragma unroll
            for (int m = 0; m < 8; ++m)
                af[m] = *(const bf16x8*)&As[bf_][(wm + m * 16 + r16) * 64 + pch];
#pragma unroll
            for (int n = 0; n < 4; ++n)
                bv[n] = *(const bf16x8*)&Bs[bf_][(wn + n * 16 + r16) * 64 + pch];
            wait_lgkm0();
            __builtin_amdgcn_s_setprio(1);
#pragma unroll
            for (int m = 0; m < 8; ++m)
#pragma unroll
                for (int n = 0; n < 4; ++n)
                    acc[m][n] = __builtin_amdgcn_mfma_f32_16x16x32_bf16(
                        af[m], bv[n], acc[m][n], 0, 0, 0);
            __builtin_amdgcn_s_setprio(0);
        }

        {
            const int pch = ((1 * 4 + quad) ^ (r16 & 7)) * 8;
            bf16x8 af[8], bv[4];
#pragma unroll
            for (int m = 0; m < 8; ++m)
                af[m] = *(const bf16x8*)&As[bf_][(wm + m * 16 + r16) * 64 + pch];
#pragma unroll
            for (int n = 0; n < 4; ++n)
                bv[n] = *(const bf16x8*)&Bs[bf_][(wn + n * 16 + r16) * 64 + pch];
            wait_lgkm0();
            raw_bar();
            if (t + 2 < NKT) STAGE(t + 2, bf_);
            __builtin_amdgcn_s_setprio(1);
#pragma unroll
            for (int m = 0; m < 8; ++m)
#pragma unroll
                for (int n = 0; n < 4; ++n)
                    acc[m][n] = __builtin_amdgcn_mfma_f32_16x16x32_bf16(
                        af[m], bv[n], acc[m][n], 0, 0, 0);
            __builtin_amdgcn_s_setprio(0);
        }
    }
#undef STAGE

#pragma unroll
    for (int m = 0; m < 8; ++m) {
        const int rbase = mtile + wm + m * 16 + quad * 4;
#pragma unroll
        for (int rr = 0; rr < 4; ++rr) {
            const int rg = rbase + rr;
            if (rg < M2) {
#pragma unroll
                for (int n = 0; n < 4; ++n) {
                    const int cg = ntile + wn + n * 16 + r16;
                    Xout[(size_t)rg * CS + cg] = acc[m][n][rr];
                }
            }
        }
    }
}

// -------------------------------------------------------------------------
extern "C" void kernel_launch(void* const* d_in, const int* in_sizes, int n_in,
                              void* d_out, int out_size, void* d_ws, size_t ws_size,
                              hipStream_t stream) {
    const float* x   = (const float*)d_in[0];   // [512, 32, 256]
    const float* Wr  = (const float*)d_in[1];   // [1840, 512]
    const float* Wi  = (const float*)d_in[2];   // [1840, 512]
    const float* ac  = (const float*)d_in[3];   // [512]
    const float* as_ = (const float*)d_in[4];   // [512]

    float* Wout = (float*)d_out;                       // [3680, 1024]
    float* Xout = (float*)d_out + (size_t)M2 * K2;     // [3680, 8192]

    __hip_bfloat16* Abf = (__hip_bfloat16*)d_ws;                                  // [3712, 512]
    __hip_bfloat16* Bxt = (__hip_bfloat16*)((char*)d_ws + (size_t)MPAD * NN * 2); // [8192, 512]

    // MEASUREMENT: prep x2, gemm x3 (all idempotent).
    // dur_new - dur_old = 1*prep + 2*gemm.
    czt_prep<<<dim3(WPREP_BLOCKS + XT_NB * XT_KB), dim3(256), 0, stream>>>(
        Wr, Wi, ac, as_, x, Wout, Abf, Bxt);
    czt_prep<<<dim3(WPREP_BLOCKS + XT_NB * XT_KB), dim3(256), 0, stream>>>(
        Wr, Wi, ac, as_, x, Wout, Abf, Bxt);
    czt_gemm<<<dim3(NBM2 * NBN2), dim3(512), 0, stream>>>(Abf, Bxt, Xout);
    czt_gemm<<<dim3(NBM2 * NBN2), dim3(512), 0, stream>>>(Abf, Bxt, Xout);
    czt_gemm<<<dim3(NBM2 * NBN2), dim3(512), 0, stream>>>(Abf, Bxt, Xout);
}

// Round 4
// 182.774 us; speedup vs baseline: 1.5284x; 1.5284x over previous
//
#include <hip/hip_runtime.h>
#include <hip/hip_bf16.h>
#include <stdint.h>

// Problem constants (CZT_72533407694901)
#define MM   1840          // M (zoom bins)
#define M2   3680          // 2M rows of W / X
#define NN   512           // N time samples
#define K2   1024          // 2N columns of W
#define CS   8192          // C*S = 32*256
#define MPAD 3712          // Abf row padding (rows 3680..3711 zero-filled by prep)

#define WPREP_BLOCKS (MPAD / 2)        // 1856 blocks, 2 rows each
#define XT_NB        (CS / 32)         // 256 n-tiles
#define XT_KB        (NN / 64)         // 8 k-tiles

// GEMM geometry (round 3): 128x256 tile, BK=64, 8 waves (2M x 4N),
// SINGLE-buffered LDS (48 KiB) -> 2 blocks/CU, 16 waves/CU (4/SIMD).
// R1 (128^2 drain) == R2 (256^2 counted-vmcnt dbuf) == ~40us proved the
// K-loop schedule is not the limiter; the serial epilogue at 1 block/CU is.
// TLP (m114) hides epilogue writes + stage drains under the co-resident
// block's MFMAs.
#define GBM 128
#define GBN 256
#define NBM 29             // 29*128 = 3712 = MPAD exactly (no clamp needed)
#define NBN 32             // 8192/256
#define NKT 8              // K=512 / BK=64

typedef __bf16 bf16x8 __attribute__((ext_vector_type(8)));
typedef float  floatx4 __attribute__((ext_vector_type(4)));

// -------------------------------------------------------------------------
// Kernel 1 (fused prep) — unchanged (verified).
// -------------------------------------------------------------------------
__global__ __launch_bounds__(256) void czt_prep(const float* __restrict__ Wr,
                                                const float* __restrict__ Wi,
                                                const float* __restrict__ ac,
                                                const float* __restrict__ as_,
                                                const float* __restrict__ x,
                                                float* __restrict__ Wout,
                                                __hip_bfloat16* __restrict__ Abf,
                                                __hip_bfloat16* __restrict__ Bxt) {
    __shared__ float tile[64 * 33];
    const int b   = blockIdx.x;
    const int tid = threadIdx.x;

    if (b < WPREP_BLOCKS) {
        const int j = b * 2 + (tid >> 7);
        const int k = (tid & 127) * 4;

        union { __hip_bfloat16 h[4]; uint2 u; } p;
        if (j < M2) {
            const int jj = (j < MM) ? j : j - MM;
            const floatx4 wr = *(const floatx4*)&Wr[(size_t)jj * NN + k];
            const floatx4 wi = *(const floatx4*)&Wi[(size_t)jj * NN + k];
            const floatx4 c  = *(const floatx4*)&ac[k];
            const floatx4 s  = *(const floatx4*)&as_[k];
            floatx4 f, g, a;
            if (j < MM) { f = wr; g = -wi; a = wr * c - wi * s; }
            else        { f = wi; g = wr;  a = wi * c + wr * s; }
#pragma unroll
            for (int e = 0; e < 4; ++e) {
                f[e] = fminf(1.f, fmaxf(-1.f, f[e]));
                g[e] = fminf(1.f, fmaxf(-1.f, g[e]));
            }
            *(floatx4*)&Wout[(size_t)j * K2 + k]      = f;
            *(floatx4*)&Wout[(size_t)j * K2 + NN + k] = g;
            p.h[0] = __float2bfloat16(a[0]);
            p.h[1] = __float2bfloat16(a[1]);
            p.h[2] = __float2bfloat16(a[2]);
            p.h[3] = __float2bfloat16(a[3]);
        } else {
            p.h[0] = p.h[1] = p.h[2] = p.h[3] = __float2bfloat16(0.0f);
        }
        *(uint2*)&Abf[(size_t)j * NN + k] = p.u;
    } else {
        const int tb = b - WPREP_BLOCKS;
        const int n0 = (tb & (XT_NB - 1)) * 32;
        const int k0 = (tb >> 8) * 64;

        const int row = tid >> 2;
        const int c8  = (tid & 3) * 8;
        const floatx4* src = (const floatx4*)&x[(size_t)(k0 + row) * CS + n0 + c8];
        const floatx4 v0 = src[0];
        const floatx4 v1 = src[1];
        float* tr = &tile[row * 33 + c8];
        tr[0] = v0[0]; tr[1] = v0[1]; tr[2] = v0[2]; tr[3] = v0[3];
        tr[4] = v1[0]; tr[5] = v1[1]; tr[6] = v1[2]; tr[7] = v1[3];
        __syncthreads();

        const int oc = tid & 7;
        const int nr = tid >> 3;
        union { __hip_bfloat16 h[8]; uint4 u; } q;
#pragma unroll
        for (int jj = 0; jj < 8; ++jj)
            q.h[jj] = __float2bfloat16(tile[(oc * 8 + jj) * 33 + nr]);
        *(uint4*)&Bxt[(size_t)(n0 + nr) * NN + k0 + oc * 8] = q.u;
    }
}

// -------------------------------------------------------------------------
// Kernel 2: GEMM  X[3680 x 8192] = A''[3680 x 512] * Bxt^T
// 128x256 tile, 8 waves, single LDS buffer, 2 blocks/CU.
// XOR source-side swizzle verbatim from the verified kernel:
// phys chunk p holds logical p^(row&7); reads fetch p=(ks*4+quad)^(r16&7).
// -------------------------------------------------------------------------
__device__ __forceinline__ void gload_lds16(const void* g, void* l) {
    __builtin_amdgcn_global_load_lds(
        (const __attribute__((address_space(1))) uint32_t*)g,
        (__attribute__((address_space(3))) uint32_t*)l,
        16, 0, 0);
}

__global__ __launch_bounds__(512, 4) void czt_gemm(const __hip_bfloat16* __restrict__ Abf,
                                                   const __hip_bfloat16* __restrict__ Bxt,
                                                   float* __restrict__ Xout) {
    __shared__ __hip_bfloat16 As[GBM * 64];   // 16 KiB
    __shared__ __hip_bfloat16 Bs[GBN * 64];   // 32 KiB

    const int tid  = threadIdx.x;
    const int lane = tid & 63;
    const int w    = tid >> 6;        // wave 0..7
    const int quad = lane >> 4;       // 0..3
    const int r16  = lane & 15;

    // XCD-aware bijective chunking: 928 blocks = 8 XCDs x 116 (116 = 4*29
    // -> each XCD owns exactly 4 n-columns: B panel 1 MB + A 3.8 MB ~ L2).
    const int b  = blockIdx.x;
    const int wk = (b & 7) * 116 + (b >> 3);
    const int mb = wk % NBM;                  // 0..28
    const int nb = wk / NBM;                  // 0..31
    const int mtile = mb * GBM;
    const int ntile = nb * GBN;

    const int wm = (w >> 2) * 64;     // wave row offset (2 M-warps)
    const int wn = (w & 3) * 64;      // wave col offset (4 N-warps)

    // Staging: per issue, 64 lanes cover 8 rows x 64 bf16 (1 KiB).
    // Wave w: A rows [w*16, w*16+16) (2 issues), B rows [w*32, w*32+32) (4).
    const int rsub   = lane >> 3;                 // row within 8-group
    const int cstage = ((lane & 7) ^ rsub) * 8;   // XOR-swizzled source col

    const __hip_bfloat16* Ag = Abf + (size_t)(mtile + w * 16 + rsub) * NN + cstage;
    const __hip_bfloat16* Bg = Bxt + (size_t)(ntile + w * 32 + rsub) * NN + cstage;

    floatx4 acc[4][4] = {};

#pragma unroll
    for (int kt = 0; kt < NKT; ++kt) {
        __syncthreads();   // previous iter's LDS reads done before overwrite
#pragma unroll
        for (int t = 0; t < 2; ++t)
            gload_lds16(Ag + (size_t)(t * 8) * NN + kt * 64,
                        &As[(w * 16 + t * 8) * 64]);
#pragma unroll
        for (int t = 0; t < 4; ++t)
            gload_lds16(Bg + (size_t)(t * 8) * NN + kt * 64,
                        &Bs[(w * 32 + t * 8) * 64]);
        __syncthreads();   // vmcnt(0) drain -> tile visible (TLP hides it)

#pragma unroll
        for (int ks = 0; ks < 2; ++ks) {
            const int pch = ((ks * 4 + quad) ^ (r16 & 7)) * 8;
            bf16x8 af[4], bv[4];
#pragma unroll
            for (int m = 0; m < 4; ++m)
                af[m] = *(const bf16x8*)&As[(wm + m * 16 + r16) * 64 + pch];
#pragma unroll
            for (int n = 0; n < 4; ++n)
                bv[n] = *(const bf16x8*)&Bs[(wn + n * 16 + r16) * 64 + pch];
#pragma unroll
            for (int m = 0; m < 4; ++m)
#pragma unroll
                for (int n = 0; n < 4; ++n)
                    acc[m][n] = __builtin_amdgcn_mfma_f32_16x16x32_bf16(
                        af[m], bv[n], acc[m][n], 0, 0, 0);
        }
    }

    // Epilogue: C/D layout col = lane&15, row = quad*4 + reg.
    // Writes overlap co-resident block's compute (2 blocks/CU).
#pragma unroll
    for (int m = 0; m < 4; ++m) {
        const int rbase = mtile + wm + m * 16 + quad * 4;
#pragma unroll
        for (int rr = 0; rr < 4; ++rr) {
            const int rg = rbase + rr;
            if (rg < M2) {
#pragma unroll
                for (int n = 0; n < 4; ++n) {
                    const int cg = ntile + wn + n * 16 + r16;
                    Xout[(size_t)rg * CS + cg] = acc[m][n][rr];
                }
            }
        }
    }
}

// -------------------------------------------------------------------------
extern "C" void kernel_launch(void* const* d_in, const int* in_sizes, int n_in,
                              void* d_out, int out_size, void* d_ws, size_t ws_size,
                              hipStream_t stream) {
    const float* x   = (const float*)d_in[0];   // [512, 32, 256]
    const float* Wr  = (const float*)d_in[1];   // [1840, 512]
    const float* Wi  = (const float*)d_in[2];   // [1840, 512]
    const float* ac  = (const float*)d_in[3];   // [512]
    const float* as_ = (const float*)d_in[4];   // [512]

    float* Wout = (float*)d_out;                       // [3680, 1024]
    float* Xout = (float*)d_out + (size_t)M2 * K2;     // [3680, 8192]

    __hip_bfloat16* Abf = (__hip_bfloat16*)d_ws;                                  // [3712, 512]
    __hip_bfloat16* Bxt = (__hip_bfloat16*)((char*)d_ws + (size_t)MPAD * NN * 2); // [8192, 512]

    czt_prep<<<dim3(WPREP_BLOCKS + XT_NB * XT_KB), dim3(256), 0, stream>>>(
        Wr, Wi, ac, as_, x, Wout, Abf, Bxt);
    czt_gemm<<<dim3(NBM * NBN), dim3(512), 0, stream>>>(Abf, Bxt, Xout);
}